// Round 15
// baseline (72.031 us; speedup 1.0000x reference)
//
#include <hip/hip_runtime.h>
#include <math.h>

#define BATCH 8
#define H 256
#define W 256
#define NPIX (BATCH * H * W)
#define NBLK2 1024  // K2: 8 img x 4 colstrips x 32 rowstrips
#define NROWS (BATCH * H)
#define HALO 32     // mask halo rows per K2 block: [rs*8-12, rs*8+19]

__device__ unsigned long long g_masks[NROWS * 4];   // 64 KB
__device__ float g_pmx[NBLK2];
__device__ float g_psb[NBLK2];
__device__ float g_psdb[NBLK2];

__device__ __forceinline__ float bce_logits(float p, float t) {
    return fmaxf(p, 0.0f) - p * t + log1pf(expf(-fabsf(p)));
}

// Exact row-EDT^2 at column p=(cs<<6)+l from the row's 4 zero-mask words.
// Fast path: 64-bit window [p-63, p+63]; else exact 4-word scan.
// Verified bit-exact in R13. Mask==0 rows yield d=1e4 -> g2=1e8.
__device__ __forceinline__ float g2_win(const unsigned long long w[4], int cs, int l) {
    const unsigned long long Wq = w[cs];
    const unsigned long long Wm = (cs > 0) ? w[cs - 1] : 0ull;
    const unsigned long long Wp = (cs < 3) ? w[cs + 1] : 0ull;
    const unsigned long long down = (Wq << (63 - l)) | ((l == 63) ? 0ull : (Wm >> (l + 1)));
    const unsigned long long up   = (Wq >> l) | ((l == 0) ? 0ull : (Wp << (64 - l)));
    int best;
    if (down | up) {
        int dd = down ? __builtin_clzll(down) : (1 << 20);
        int du = up   ? __builtin_ctzll(up)   : (1 << 20);
        best = min(dd, du);
    } else {
        const int p = (cs << 6) + l;
        best = 1 << 20;
        #pragma unroll
        for (int q = 0; q < 4; ++q) {
            const int rel = p - (q << 6);
            const unsigned long long m = w[q];
            unsigned long long mlo = (rel < 0)  ? 0ull
                                   : (rel >= 63) ? m : (m & ((2ull << rel) - 1ull));
            unsigned long long mhi = (rel <= 0) ? m
                                   : (rel > 63)  ? 0ull : (m & (~0ull << rel));
            if (mlo) best = min(best, rel - (63 - __builtin_clzll(mlo)));
            if (mhi) best = min(best, __builtin_ctzll(mhi) - rel);
        }
    }
    float d = (best > 255) ? 1e4f : (float)best;
    return d * d;
}

// K1: zero-pixel bitmasks per row (reads 8 MB coalesced, writes 64 KB).
__global__ void __launch_bounds__(256) make_masks(const float* __restrict__ target) {
    const int wv = threadIdx.x >> 6, l = threadIdx.x & 63;
    const int r = blockIdx.x * 4 + wv;             // 0..2047
    const float* trow = target + (size_t)r * W;
    float t0 = trow[l], t1 = trow[l + 64], t2 = trow[l + 128], t3 = trow[l + 192];
    unsigned long long m0 = __ballot(t0 == 0.0f);
    unsigned long long m1 = __ballot(t1 == 0.0f);
    unsigned long long m2 = __ballot(t2 == 0.0f);
    unsigned long long m3 = __ballot(t3 == 0.0f);
    if (l < 4) {
        unsigned long long m = (l == 0) ? m0 : (l == 1) ? m1 : (l == 2) ? m2 : m3;
        g_masks[(size_t)r * 4 + l] = m;
    }
}

// K2: column envelope from an LDS mask halo (g2 computed in-register via
// window scan), pipelined prologue + bit-exact early-exit tail, fused BCE.
// Lane = column; thread owns rows i0, i0+1. No g2 intermediate in memory.
__global__ void __launch_bounds__(256) envelope_bce(
        const float* __restrict__ pred, const float* __restrict__ target) {
    __shared__ unsigned long long mh[HALO][4];    // 1 KB mask halo
    __shared__ float red[3][4];
    const int tid = threadIdx.x;
    const int wv = tid >> 6, l = tid & 63;
    const int b  = blockIdx.x >> 7;               // image (128 blocks each)
    const int cs = (blockIdx.x >> 5) & 3;         // column strip (64 cols)
    const int rs = blockIdx.x & 31;               // row strip (8 rows)
    const int c  = (cs << 6) + l;                 // this lane's column
    const int i0 = (rs << 3) + (wv << 1);         // rows i0, i0+1
    const int hlo = (rs << 3) - 12;               // halo rows [hlo, hlo+31]

    // BCE pixel loads issued early (consumed at the end)
    const size_t po = ((size_t)(b * H + i0)) * W + c;
    float p0 = pred[po], p1 = pred[po + W];
    float t0 = target[po], t1 = target[po + W];

    // ---- Load mask halo: 32 rows x 4 words; OOB rows -> 0 (g2=1e8 sentinel:
    // 1e8+e^2 (e>=1) never beats the always-present k=i candidate; bit-exact).
    if (tid < HALO * 4) {
        const int hr = hlo + (tid >> 2);
        unsigned long long m = 0ull;
        if (hr >= 0 && hr < H) m = g_masks[(((size_t)(b * H + hr)) << 2) | (tid & 3)];
        mh[tid >> 2][tid & 3] = m;
    }
    __syncthreads();

    float acc0 = 3.0e38f, acc1 = 3.0e38f;
    // ---- Prologue: P steps each way, unconditional; rows in-halo by design.
    // fmaf(e,e,g) == reference g2 + (i-k)^2 (exact integers < 2^24, one rounding).
    const int P = 10;
    #pragma unroll
    for (int s = 0; s < P; ++s) {
        const int kd = i0 + 1 - s;                // >= rs*8-8 >= hlo+4
        const int ku = i0 + 2 + s;                // <= rs*8+17 <= hlo+29
        float gd = g2_win(mh[kd - hlo], cs, l);
        float gu = g2_win(mh[ku - hlo], cs, l);
        const float ed0 = (float)(s - 1), ed1 = (float)s;       // r - kd
        const float eu0 = (float)(s + 2), eu1 = (float)(s + 1); // ku - r
        acc0 = fminf(acc0, fminf(fmaf(ed0, ed0, gd), fmaf(eu0, eu0, gu)));
        acc1 = fminf(acc1, fminf(fmaf(ed1, ed1, gd), fmaf(eu1, eu1, gu)));
    }

    // ---- Tail: exact early-exit two-pointer scan (rarely runs).
    int kd = i0 + 1 - P, ku = i0 + 2 + P;
    float fd0 = (float)(i0 - kd);
    float fu0 = (float)(ku - i0);
    for (;;) {
        float maxacc = fmaxf(acc0, acc1);
        float dn = (float)(i0 - kd);
        float up = (float)(ku - (i0 + 1));
        bool alive = (kd >= 0 && dn * dn <= maxacc) || (ku <= 255 && up * up <= maxacc);
        if (!__any(alive)) break;
        if (kd >= 0) {
            float g;
            if (kd >= hlo) g = g2_win(mh[kd - hlo], cs, l);
            else {
                unsigned long long w[4];
                #pragma unroll
                for (int q = 0; q < 4; ++q) w[q] = g_masks[(((size_t)(b * H + kd)) << 2) | q];
                g = g2_win(w, cs, l);
            }
            acc0 = fminf(acc0, fmaf(fd0, fd0, g));
            float fd1 = fd0 + 1.0f;
            acc1 = fminf(acc1, fmaf(fd1, fd1, g));
        }
        if (ku <= 255) {
            float g;
            if (ku - hlo < HALO) g = g2_win(mh[ku - hlo], cs, l);
            else {
                unsigned long long w[4];
                #pragma unroll
                for (int q = 0; q < 4; ++q) w[q] = g_masks[(((size_t)(b * H + ku)) << 2) | q];
                g = g2_win(w, cs, l);
            }
            float fu1 = fu0 - 1.0f;
            acc0 = fminf(acc0, fmaf(fu0, fu0, g));
            acc1 = fminf(acc1, fmaf(fu1, fu1, g));
        }
        --kd; ++ku; fd0 += 1.0f; fu0 += 1.0f;
    }

    // ---- Epilogue: fused BCE + per-block partials ----
    float mx = fmaxf(acc0, acc1);
    float b0 = bce_logits(p0, t0), b1 = bce_logits(p1, t1);
    float sb  = b0 + b1;
    float sdb = sqrtf(acc0) * b0 + sqrtf(acc1) * b1;

    #pragma unroll
    for (int o = 32; o > 0; o >>= 1) {
        mx  = fmaxf(mx, __shfl_down(mx, o, 64));
        sb  += __shfl_down(sb, o, 64);
        sdb += __shfl_down(sdb, o, 64);
    }
    if (l == 0) { red[0][wv] = mx; red[1][wv] = sb; red[2][wv] = sdb; }
    __syncthreads();
    if (tid == 0) {
        g_pmx [blockIdx.x] = fmaxf(fmaxf(red[0][0], red[0][1]), fmaxf(red[0][2], red[0][3]));
        g_psb [blockIdx.x] = (red[1][0] + red[1][1]) + (red[1][2] + red[1][3]);
        g_psdb[blockIdx.x] = (red[2][0] + red[2][1]) + (red[2][2] + red[2][3]);
    }
}

// K3: 1024 partials -> scalar. Images are contiguous 128-block runs.
__global__ void final_reduce(float* __restrict__ out) {
    const int tid = threadIdx.x;
    const int img = tid >> 5, j = tid & 31;        // 8 images x 32 threads
    float mx = 0.0f, sb = 0.0f, sdb = 0.0f;
    #pragma unroll
    for (int q = 0; q < 4; ++q) {
        const int e = (img << 7) + j + (q << 5);
        mx  = fmaxf(mx, g_pmx[e]);
        sb  += g_psb[e];
        sdb += g_psdb[e];
    }
    #pragma unroll
    for (int o = 16; o > 0; o >>= 1) {             // width-32 groups stay per-image
        mx  = fmaxf(mx, __shfl_down(mx, o, 32));
        sb  += __shfl_down(sb, o, 32);
        sdb += __shfl_down(sdb, o, 32);
    }
    __shared__ float cimg[8], simg[8];
    if (j == 0) {
        cimg[img] = sdb / (sqrtf(mx) + 1e-7f);     // sqrt commutes with max
        simg[img] = sb;
    }
    __syncthreads();
    if (tid == 0) {
        float tot = 0.0f;
        #pragma unroll
        for (int i = 0; i < 8; ++i) tot += simg[i] + cimg[i];
        out[0] = tot * (1.0f / (float)NPIX);
    }
}

extern "C" void kernel_launch(void* const* d_in, const int* in_sizes, int n_in,
                              void* d_out, int out_size, void* d_ws, size_t ws_size,
                              hipStream_t stream) {
    const float* pred   = (const float*)d_in[0];
    const float* target = (const float*)d_in[1];
    (void)d_ws; (void)ws_size;

    make_masks<<<NROWS / 4, 256, 0, stream>>>(target);            // 512 blocks
    envelope_bce<<<NBLK2, 256, 0, stream>>>(pred, target);
    final_reduce<<<1, 256, 0, stream>>>((float*)d_out);
}

// Round 16
// 65.085 us; speedup vs baseline: 1.1067x; 1.1067x over previous
//
#include <hip/hip_runtime.h>
#include <math.h>

#define BATCH 8
#define H 256
#define W 256
#define NPIX (BATCH * H * W)
#define NBLK2 1024  // K2: 8 img x 4 colstrips x 32 rowstrips

__device__ __forceinline__ float bce_logits(float p, float t) {
    return fmaxf(p, 0.0f) - p * t + log1pf(expf(-fabsf(p)));
}

// K1: row EDT via ballot masks; stores d as ushort (d in [0,255] or 10000=INF).
// Layout d16[b*65536 + r*256 + w]. Block = (image, row-quad), thread = column.
__global__ void __launch_bounds__(256) row_edt(const float* __restrict__ target,
                                               unsigned short* __restrict__ d16) {
    __shared__ unsigned long long mlds[4][4];
    const int tid = threadIdx.x;
    const int v = tid >> 6, l = tid & 63;
    const float* imgr = target + (size_t)blockIdx.x * 4 * W;

    #pragma unroll
    for (int j = 0; j < 4; ++j) {
        float t = imgr[j * W + tid];
        unsigned long long m = __ballot(t == 0.0f);
        if (l == 0) mlds[j][v] = m;
    }
    __syncthreads();

    const int p = tid;                     // column
    #pragma unroll
    for (int j = 0; j < 4; ++j) {
        unsigned long long mw[4] = {mlds[j][0], mlds[j][1], mlds[j][2], mlds[j][3]};
        int best = 1 << 20;
        #pragma unroll
        for (int w = 0; w < 4; ++w) {
            const int rel = p - (w << 6);
            const unsigned long long m = mw[w];
            unsigned long long mlo = (rel < 0)  ? 0ull
                                   : (rel >= 63) ? m : (m & ((2ull << rel) - 1ull));
            unsigned long long mhi = (rel <= 0) ? m
                                   : (rel > 63)  ? 0ull : (m & (~0ull << rel));
            if (mlo) best = min(best, rel - (63 - __builtin_clzll(mlo)));
            if (mhi) best = min(best, __builtin_ctzll(mhi) - rel);
        }
        d16[(size_t)blockIdx.x * 4 * W + j * W + tid] =
            (best > 255) ? (unsigned short)10000 : (unsigned short)best;  // INF per ref
    }
}

// K2: column envelope (pipelined prologue + bit-exact early-exit tail) + BCE.
// Lane = column; thread owns rows i0, i0+1. g2 = ((float)d)^2 computed inline
// (exact: integers < 2^24; 1e4^2 = 1e8 exact). target is NOT read: t = (d2>0),
// exact because acc includes the k=i candidate (acc==0 <=> pixel is zero).
__global__ void __launch_bounds__(256) envelope_bce(
        const unsigned short* __restrict__ d16, const float* __restrict__ pred,
        float* __restrict__ pmx, float* __restrict__ psb, float* __restrict__ psdb) {
    __shared__ float red[3][4];
    const int tid = threadIdx.x;
    const int wv = tid >> 6, l = tid & 63;
    const int b  = blockIdx.x >> 7;               // image (128 blocks each)
    const int cs = (blockIdx.x >> 5) & 3;         // column strip (64 cols)
    const int rs = blockIdx.x & 31;               // row strip (8 rows)
    const int c  = (cs << 6) + l;                 // this lane's column
    const int i0 = (rs << 3) + (wv << 1);         // rows i0, i0+1

    // pred loads issued early (consumed at the end)
    const size_t po = ((size_t)(b * H + i0)) * W + c;
    float p0 = pred[po], p1 = pred[po + W];

    const unsigned short* gcol = d16 + (size_t)b * H * W + c;

    float acc0 = 3.0e38f, acc1 = 3.0e38f;
    // Prologue: P steps each way, unconditional (clamped + OOB sentinel).
    // Includes k=i0 (s=1, ed0=0) and k=i0+1 (s=0, ed1=0) -> acc==0 iff t==0.
    const int P = 10;
    #pragma unroll
    for (int s = 0; s < P; ++s) {
        const int kd = i0 + 1 - s;
        const int ku = i0 + 2 + s;
        float dd = (float)gcol[(size_t)max(kd, 0) * W];
        float du = (float)gcol[(size_t)min(ku, 255) * W];
        float gd = dd * dd, gu = du * du;         // exact squares
        if (kd < 0)   gd = 3.0e38f;
        if (ku > 255) gu = 3.0e38f;
        const float ed0 = (float)(s - 1), ed1 = (float)s;       // r - kd
        const float eu0 = (float)(s + 2), eu1 = (float)(s + 1); // ku - r
        acc0 = fminf(acc0, fminf(fmaf(ed0, ed0, gd), fmaf(eu0, eu0, gu)));
        acc1 = fminf(acc1, fminf(fmaf(ed1, ed1, gd), fmaf(eu1, eu1, gu)));
    }

    // Tail: exact early-exit two-pointer scan (rarely runs).
    int kd = i0 + 1 - P, ku = i0 + 2 + P;
    float fd0 = (float)(i0 - kd);
    float fu0 = (float)(ku - i0);
    for (;;) {
        float maxacc = fmaxf(acc0, acc1);
        float dn = (float)(i0 - kd);
        float up = (float)(ku - (i0 + 1));
        bool alive = (kd >= 0 && dn * dn <= maxacc) || (ku <= 255 && up * up <= maxacc);
        if (!__any(alive)) break;
        if (kd >= 0) {
            float dv = (float)gcol[(size_t)kd * W];
            float g = dv * dv;
            acc0 = fminf(acc0, fmaf(fd0, fd0, g));
            float fd1 = fd0 + 1.0f;
            acc1 = fminf(acc1, fmaf(fd1, fd1, g));
        }
        if (ku <= 255) {
            float dv = (float)gcol[(size_t)ku * W];
            float g = dv * dv;
            float fu1 = fu0 - 1.0f;
            acc0 = fminf(acc0, fmaf(fu0, fu0, g));
            acc1 = fminf(acc1, fmaf(fu1, fu1, g));
        }
        --kd; ++ku; fd0 += 1.0f; fu0 += 1.0f;
    }

    // Epilogue: fused BCE (t derived from acc) + per-block partials.
    float t0 = (acc0 == 0.0f) ? 0.0f : 1.0f;      // exact: d2==0 <=> target==0
    float t1 = (acc1 == 0.0f) ? 0.0f : 1.0f;
    float mx = fmaxf(acc0, acc1);
    float b0 = bce_logits(p0, t0), b1 = bce_logits(p1, t1);
    float sb  = b0 + b1;
    float sdb = sqrtf(acc0) * b0 + sqrtf(acc1) * b1;

    #pragma unroll
    for (int o = 32; o > 0; o >>= 1) {
        mx  = fmaxf(mx, __shfl_down(mx, o, 64));
        sb  += __shfl_down(sb, o, 64);
        sdb += __shfl_down(sdb, o, 64);
    }
    if (l == 0) { red[0][wv] = mx; red[1][wv] = sb; red[2][wv] = sdb; }
    __syncthreads();
    if (tid == 0) {
        pmx [blockIdx.x] = fmaxf(fmaxf(red[0][0], red[0][1]), fmaxf(red[0][2], red[0][3]));
        psb [blockIdx.x] = (red[1][0] + red[1][1]) + (red[1][2] + red[1][3]);
        psdb[blockIdx.x] = (red[2][0] + red[2][1]) + (red[2][2] + red[2][3]);
    }
}

// K3: 1024 partials -> scalar. Images are contiguous 128-block runs.
__global__ void final_reduce(const float* __restrict__ pmx, const float* __restrict__ psb,
                             const float* __restrict__ psdb, float* __restrict__ out) {
    const int tid = threadIdx.x;
    const int img = tid >> 5, j = tid & 31;        // 8 images x 32 threads
    float mx = 0.0f, sb = 0.0f, sdb = 0.0f;
    #pragma unroll
    for (int q = 0; q < 4; ++q) {
        const int e = (img << 7) + j + (q << 5);
        mx  = fmaxf(mx, pmx[e]);
        sb  += psb[e];
        sdb += psdb[e];
    }
    #pragma unroll
    for (int o = 16; o > 0; o >>= 1) {             // width-32 groups stay per-image
        mx  = fmaxf(mx, __shfl_down(mx, o, 32));
        sb  += __shfl_down(sb, o, 32);
        sdb += __shfl_down(sdb, o, 32);
    }
    __shared__ float cimg[8], simg[8];
    if (j == 0) {
        cimg[img] = sdb / (sqrtf(mx) + 1e-7f);     // sqrt commutes with max
        simg[img] = sb;
    }
    __syncthreads();
    if (tid == 0) {
        float tot = 0.0f;
        #pragma unroll
        for (int i = 0; i < 8; ++i) tot += simg[i] + cimg[i];
        out[0] = tot * (1.0f / (float)NPIX);
    }
}

extern "C" void kernel_launch(void* const* d_in, const int* in_sizes, int n_in,
                              void* d_out, int out_size, void* d_ws, size_t ws_size,
                              hipStream_t stream) {
    const float* pred   = (const float*)d_in[0];
    const float* target = (const float*)d_in[1];

    unsigned short* d16 = (unsigned short*)d_ws;                  // 1 MB
    float* pmx  = (float*)((char*)d_ws + (size_t)NPIX * sizeof(unsigned short));
    float* psb  = pmx + NBLK2;
    float* psdb = psb + NBLK2;

    row_edt<<<BATCH * 64, 256, 0, stream>>>(target, d16);         // 512 blocks
    envelope_bce<<<NBLK2, 256, 0, stream>>>(d16, pred, pmx, psb, psdb);
    final_reduce<<<1, 256, 0, stream>>>(pmx, psb, psdb, (float*)d_out);
}